// Round 1
// 217.568 us; speedup vs baseline: 1.0567x; 1.0567x over previous
//
#include <hip/hip_runtime.h>
#include <math.h>

#define D_DIM 256
#define HW 16384
#define C 19
#define N_PX 131072
#define EPS 1e-8f

#define S_SC  1048576.0f       // 2^20 fixed point for class sums (|sum| < ~500)
#define IS_S  (1.0f/1048576.0f)
#define U_SC  16777216.0f      // 2^24 fixed point for unit-vector sums (|sum| < ~30)
#define IS_U  (1.0f/16777216.0f)

// ws layout in 4-byte words
#define OFF_S    0        // int[4864] class sums Σf, fixed-point
#define OFF_U    4864     // int[4864] class unit sums Σf/||f||, fixed-point
#define OFF_CNT  9728     // int[19]   class counts (+13 pad words to 9760)
#define WS_ZERO  9760
#define OFF_PART 9760     // int[512][9760] per-block partials (20 MB)
#define PSTRIDE  9760     // row stride, 16B-divisible
#define G1       512

// ---------- K0: zero final accumulators ----------
__global__ void k0_zero(int* __restrict__ ws) {
    int i = blockIdx.x * blockDim.x + threadIdx.x;
    if (i < WS_ZERO) ws[i] = 0;
}

// ---------- K1: single-pass, register-resident tile ----------
// grid 512: block owns 256 px (2 rounds of 128). 256 thr = 32 px-quads (qq) × 8
// channel sub-lanes (dq). Thread holds 4 px × 32 ch (channels g*8+dq) in 32 float4
// regs; norms via 3× __shfl_xor across dq lanes (no LDS, no mid-round barrier);
// atomics spread over 8 dd values/instr so same-address multiplicity ~1-2 (was ~8).
__global__ __launch_bounds__(256, 2) void k1_pass(const float* __restrict__ in,
                                                  const int* __restrict__ tgt,
                                                  int* __restrict__ wsi) {
    __shared__ int sS[C * 257];      // stride 257: bank = (label + 8g + dq) & 31
    __shared__ int sU[C * 257];
    __shared__ int s_cnt[C];
    const int tid = threadIdx.x;
    const int dq  = tid & 7;         // channel sub-lane: channels g*8+dq
    const int qq  = tid >> 3;        // pixel quad within round

    for (int i = tid; i < C * 257; i += 256) { sS[i] = 0; sU[i] = 0; }
    if (tid < C) s_cnt[tid] = 0;
    __syncthreads();

    const int px0 = blockIdx.x << 8;          // 256 px per block (64 blocks/image)
    const int b   = px0 >> 14;
    const float* bbase = in + (((size_t)(b * D_DIM + dq)) << 14);

    #pragma unroll
    for (int r = 0; r < 2; ++r) {
        const int hwq = (px0 & (HW - 1)) + (r << 7) + (qq << 2);
        const int p   = px0 + (r << 7) + (qq << 2);
        const int4 lab = *(const int4*)(tgt + p);
        if (dq == 0) {
            atomicAdd(&s_cnt[lab.x], 1); atomicAdd(&s_cnt[lab.y], 1);
            atomicAdd(&s_cnt[lab.z], 1); atomicAdd(&s_cnt[lab.w], 1);
        }

        // load 4 px × 32 channels into registers (channel plane g*8+dq)
        const float* base = bbase + hwq;
        float4 v[32];
        #pragma unroll
        for (int g = 0; g < 32; ++g)
            v[g] = *(const float4*)(base + ((size_t)g << 17));

        // per-px partial ||f||^2 over this lane's 32 channels
        float4 nf = {0.f, 0.f, 0.f, 0.f};
        #pragma unroll
        for (int g = 0; g < 32; ++g) {
            nf.x += v[g].x * v[g].x; nf.y += v[g].y * v[g].y;
            nf.z += v[g].z * v[g].z; nf.w += v[g].w * v[g].w;
        }
        // butterfly across the 8 dq lanes (lane bits 0..2) -> full 256-ch norms
        #pragma unroll
        for (int m = 1; m <= 4; m <<= 1) {
            nf.x += __shfl_xor(nf.x, m, 64);
            nf.y += __shfl_xor(nf.y, m, 64);
            nf.z += __shfl_xor(nf.z, m, 64);
            nf.w += __shfl_xor(nf.w, m, 64);
        }
        const float sa = nf.x > 0.f ? U_SC / sqrtf(nf.x) : 0.f;
        const float sb = nf.y > 0.f ? U_SC / sqrtf(nf.y) : 0.f;
        const float sc = nf.z > 0.f ? U_SC / sqrtf(nf.z) : 0.f;
        const float sd = nf.w > 0.f ? U_SC / sqrtf(nf.w) : 0.f;

        const int rowa = lab.x * 257, rowb = lab.y * 257,
                  rowc = lab.z * 257, rowd = lab.w * 257;
        #pragma unroll
        for (int g = 0; g < 32; ++g) {
            const int dd = (g << 3) + dq;
            atomicAdd(&sS[rowa + dd], __float2int_rn(v[g].x * S_SC));
            atomicAdd(&sS[rowb + dd], __float2int_rn(v[g].y * S_SC));
            atomicAdd(&sS[rowc + dd], __float2int_rn(v[g].z * S_SC));
            atomicAdd(&sS[rowd + dd], __float2int_rn(v[g].w * S_SC));
            atomicAdd(&sU[rowa + dd], __float2int_rn(v[g].x * sa));
            atomicAdd(&sU[rowb + dd], __float2int_rn(v[g].y * sb));
            atomicAdd(&sU[rowc + dd], __float2int_rn(v[g].z * sc));
            atomicAdd(&sU[rowd + dd], __float2int_rn(v[g].w * sd));
        }
    }
    __syncthreads();   // order LDS atomics before writeout

    // plain coalesced writeout of this block's partial row (NO global atomics)
    int* __restrict__ row = wsi + OFF_PART + (size_t)blockIdx.x * PSTRIDE;
    for (int i = tid; i < C * 256; i += 256) {
        int c = i >> 8, d = i & 255;
        row[OFF_S + i] = sS[c * 257 + d];
        row[OFF_U + i] = sU[c * 257 + d];
    }
    if (tid < C)                 row[OFF_CNT + tid] = s_cnt[tid];
    else if (tid < 32)           row[OFF_CNT + tid] = 0;   // pad to 9760
}

// ---------- K1b: reduce 512 partial rows -> final arrays ----------
// grid (10, 32): block sums 16 rows for 1024 columns (int4), 4 atomics/thread to finish.
__global__ __launch_bounds__(256) void k1b_reduce(int* __restrict__ wsi) {
    const int col4 = blockIdx.x * 256 + threadIdx.x;     // int4 column index
    if (col4 >= PSTRIDE / 4) return;
    const int4* base = (const int4*)(wsi + OFF_PART)
                     + (size_t)blockIdx.y * 16 * (PSTRIDE / 4) + col4;
    int4 acc = {0, 0, 0, 0};
    #pragma unroll
    for (int r = 0; r < 16; ++r) {
        int4 v = base[(size_t)r * (PSTRIDE / 4)];
        acc.x += v.x; acc.y += v.y; acc.z += v.z; acc.w += v.w;
    }
    atomicAdd(&wsi[col4 * 4 + 0], acc.x);
    atomicAdd(&wsi[col4 * 4 + 1], acc.y);
    atomicAdd(&wsi[col4 * 4 + 2], acc.z);
    atomicAdd(&wsi[col4 * 4 + 3], acc.w);
}

// ---------- K2: centers, norms, Gram/diff, sim, final (1 block, 8 waves) ----------
__global__ __launch_bounds__(512) void k2_final(const int* __restrict__ wsi,
                                                float* __restrict__ out) {
    __shared__ __align__(16) float s_cen[C * 260];  // 260 = 65 float4: rows 16B-aligned
    __shared__ __align__(16) float s_u[C * 260];
    __shared__ float s_nc[C];
    __shared__ float s_cntf[C];
    __shared__ float s_pair[C * C];
    __shared__ float s_sim[C];
    const int tid = threadIdx.x;

    if (tid < C) s_cntf[tid] = (float)wsi[OFF_CNT + tid];
    __syncthreads();
    for (int i = tid; i < C * 256; i += 512) {
        int c = i >> 8, d = i & 255;
        float icnt = 1.f / fmaxf(s_cntf[c], 1.f);
        s_cen[c * 260 + d] = (float)wsi[OFF_S + i] * IS_S * icnt;
        s_u[c * 260 + d]   = (float)wsi[OFF_U + i] * IS_U;
    }
    __syncthreads();
    if (tid < C) {
        float nsq = 0.f;
        for (int d = 0; d < D_DIM; ++d) {
            float x = s_cen[tid * 260 + d];
            nsq += x * x;
        }
        s_nc[tid] = sqrtf(nsq);
    }
    __syncthreads();
    if (tid < C * C) {                       // waves 0-5: Gram + diff pairs
        int i = tid / C, j = tid % C;
        const float4* ci = (const float4*)&s_cen[i * 260];
        const float4* cj = (const float4*)&s_cen[j * 260];
        float dot = 0.f;
        #pragma unroll 8
        for (int k = 0; k < 64; ++k) {
            float4 a = ci[k], bb = cj[k];
            dot += a.x * bb.x + a.y * bb.y + a.z * bb.z + a.w * bb.w;
        }
        float S = dot / fmaxf(s_nc[i] * s_nc[j], EPS);
        s_pair[tid] = (i == j) ? (1.f - S) : fmaxf(S, 0.f);
    } else if (tid >= 384 && tid < 384 + C) { // wave 6: sim dots, concurrent with Gram
        int i = tid - 384;
        const float4* ci = (const float4*)&s_cen[i * 260];
        const float4* ui = (const float4*)&s_u[i * 260];
        float dot = 0.f;
        #pragma unroll 8
        for (int k = 0; k < 64; ++k) {
            float4 a = ci[k], bb = ui[k];
            dot += a.x * bb.x + a.y * bb.y + a.z * bb.z + a.w * bb.w;
        }
        // sim_i = 1 - (Σ cos)/cnt = 1 - dot(center,U)/(nc*cnt)
        s_sim[i] = (s_cntf[i] > 0.f)
                 ? (1.f - dot / fmaxf(s_nc[i] * s_cntf[i], EPS)) : 0.f;
    }
    __syncthreads();
    if (tid < C) {
        float row = 0.f;
        for (int j = 0; j < C; ++j) row += s_pair[tid * C + j];
        s_pair[tid * C] = (s_cntf[tid] > 0.f) ? (row * (1.f / (float)C)) : 0.f;
    }
    __syncthreads();
    if (tid == 0) {
        float tot = 0.f;
        for (int i = 0; i < C; ++i) tot += s_pair[i * C] + s_sim[i];
        out[0] = tot;
    }
}

extern "C" void kernel_launch(void* const* d_in, const int* in_sizes, int n_in,
                              void* d_out, int out_size, void* d_ws, size_t ws_size,
                              hipStream_t stream) {
    const float* in  = (const float*)d_in[0];
    const int*   tgt = (const int*)d_in[1];
    float* out = (float*)d_out;
    int*   wsi = (int*)d_ws;

    k0_zero<<<39, 256, 0, stream>>>(wsi);
    k1_pass<<<G1, 256, 0, stream>>>(in, tgt, wsi);
    k1b_reduce<<<dim3(10, 32), 256, 0, stream>>>(wsi);
    k2_final<<<1, 512, 0, stream>>>(wsi, out);
}

// Round 2
// 216.675 us; speedup vs baseline: 1.0611x; 1.0041x over previous
//
#include <hip/hip_runtime.h>
#include <math.h>

#define D_DIM 256
#define HW 16384
#define C 19
#define N_PX 131072
#define EPS 1e-8f

#define S_SC  1048576.0f       // 2^20 fixed point for class sums (|sum| < ~500)
#define IS_S  (1.0f/1048576.0f)
#define U_SC  16777216.0f      // 2^24 fixed point for unit-vector sums (|sum| < ~30)
#define IS_U  (1.0f/16777216.0f)

// ws layout in 4-byte words
#define OFF_S    0        // int[4864] class sums Σf, fixed-point
#define OFF_U    4864     // int[4864] class unit sums Σf/||f||, fixed-point
#define OFF_CNT  9728     // int[19]   class counts (+13 pad words to 9760)
#define WS_ZERO  9760
#define OFF_PART 9760     // int[512][9760] per-block partials (20 MB)
#define PSTRIDE  9760     // row stride, 16B-divisible
#define G1       512

// ---------- K1: single-pass, register-resident tile, 512-thread blocks ----------
// grid 512: block owns 256 px (2 rounds of 128). 512 thr = 32 px-quads (qq) × 16
// channel sub-lanes (dq). Thread holds 4 px × 16 ch (channels g*16+dq) in 16 float4
// regs (64 VGPR data -> total <=128 -> 4 waves/SIMD, 16 waves/CU: 2x TLP vs prev).
// Norms via 4× __shfl_xor across the 16 dq lanes; atomics spread over 16 dd values
// per instruction. Final-accumulator zeroing folded in (k0 dropped): safe because
// k1b (only toucher of ws[0..WS_ZERO)) launches after k1 completes.
__global__ __launch_bounds__(512, 4) void k1_pass(const float* __restrict__ in,
                                                  const int* __restrict__ tgt,
                                                  int* __restrict__ wsi) {
    __shared__ int sS[C * 257];      // stride 257: bank = (label + 16g + dq) & 31
    __shared__ int sU[C * 257];
    __shared__ int s_cnt[C];
    const int tid = threadIdx.x;
    const int dq  = tid & 15;        // channel sub-lane: channels g*16+dq
    const int qq  = tid >> 4;        // pixel quad within round (0..31)

    for (int i = tid; i < C * 257; i += 512) { sS[i] = 0; sU[i] = 0; }
    if (tid < C) s_cnt[tid] = 0;
    // folded k0: zero final accumulators (20 blocks x 512 words covers 9760+)
    if (blockIdx.x < 20) {
        int i = (blockIdx.x << 9) + tid;
        if (i < WS_ZERO) wsi[i] = 0;
    }
    __syncthreads();

    const int px0 = blockIdx.x << 8;          // 256 px per block (64 blocks/image)
    const int b   = px0 >> 14;
    const float* bbase = in + (((size_t)(b * D_DIM + dq)) << 14);

    #pragma unroll
    for (int r = 0; r < 2; ++r) {
        const int hwq = (px0 & (HW - 1)) + (r << 7) + (qq << 2);
        const int p   = px0 + (r << 7) + (qq << 2);
        const int4 lab = *(const int4*)(tgt + p);
        if (dq == 0) {
            atomicAdd(&s_cnt[lab.x], 1); atomicAdd(&s_cnt[lab.y], 1);
            atomicAdd(&s_cnt[lab.z], 1); atomicAdd(&s_cnt[lab.w], 1);
        }

        // load 4 px × 16 channels into registers (channel plane g*16+dq)
        const float* base = bbase + hwq;
        float4 v[16];
        #pragma unroll
        for (int g = 0; g < 16; ++g)
            v[g] = *(const float4*)(base + ((size_t)g << 18));  // 16 ch = 1 MiB stride

        // per-px partial ||f||^2 over this lane's 16 channels
        float4 nf = {0.f, 0.f, 0.f, 0.f};
        #pragma unroll
        for (int g = 0; g < 16; ++g) {
            nf.x += v[g].x * v[g].x; nf.y += v[g].y * v[g].y;
            nf.z += v[g].z * v[g].z; nf.w += v[g].w * v[g].w;
        }
        // butterfly across the 16 dq lanes (lane bits 0..3) -> full 256-ch norms
        #pragma unroll
        for (int m = 1; m <= 8; m <<= 1) {
            nf.x += __shfl_xor(nf.x, m, 64);
            nf.y += __shfl_xor(nf.y, m, 64);
            nf.z += __shfl_xor(nf.z, m, 64);
            nf.w += __shfl_xor(nf.w, m, 64);
        }
        const float sa = nf.x > 0.f ? U_SC / sqrtf(nf.x) : 0.f;
        const float sb = nf.y > 0.f ? U_SC / sqrtf(nf.y) : 0.f;
        const float sc = nf.z > 0.f ? U_SC / sqrtf(nf.z) : 0.f;
        const float sd = nf.w > 0.f ? U_SC / sqrtf(nf.w) : 0.f;

        const int rowa = lab.x * 257, rowb = lab.y * 257,
                  rowc = lab.z * 257, rowd = lab.w * 257;
        #pragma unroll
        for (int g = 0; g < 16; ++g) {
            const int dd = (g << 4) + dq;
            atomicAdd(&sS[rowa + dd], __float2int_rn(v[g].x * S_SC));
            atomicAdd(&sS[rowb + dd], __float2int_rn(v[g].y * S_SC));
            atomicAdd(&sS[rowc + dd], __float2int_rn(v[g].z * S_SC));
            atomicAdd(&sS[rowd + dd], __float2int_rn(v[g].w * S_SC));
            atomicAdd(&sU[rowa + dd], __float2int_rn(v[g].x * sa));
            atomicAdd(&sU[rowb + dd], __float2int_rn(v[g].y * sb));
            atomicAdd(&sU[rowc + dd], __float2int_rn(v[g].z * sc));
            atomicAdd(&sU[rowd + dd], __float2int_rn(v[g].w * sd));
        }
    }
    __syncthreads();   // order LDS atomics before writeout

    // plain coalesced writeout of this block's partial row (NO global atomics)
    int* __restrict__ row = wsi + OFF_PART + (size_t)blockIdx.x * PSTRIDE;
    for (int i = tid; i < C * 256; i += 512) {
        int c = i >> 8, d = i & 255;
        row[OFF_S + i] = sS[c * 257 + d];
        row[OFF_U + i] = sU[c * 257 + d];
    }
    if (tid < C)                 row[OFF_CNT + tid] = s_cnt[tid];
    else if (tid < 32)           row[OFF_CNT + tid] = 0;   // pad to 9760
}

// ---------- K1b: reduce 512 partial rows -> final arrays ----------
// grid (10, 32): block sums 16 rows for 1024 columns (int4), 4 atomics/thread to finish.
__global__ __launch_bounds__(256) void k1b_reduce(int* __restrict__ wsi) {
    const int col4 = blockIdx.x * 256 + threadIdx.x;     // int4 column index
    if (col4 >= PSTRIDE / 4) return;
    const int4* base = (const int4*)(wsi + OFF_PART)
                     + (size_t)blockIdx.y * 16 * (PSTRIDE / 4) + col4;
    int4 acc = {0, 0, 0, 0};
    #pragma unroll
    for (int r = 0; r < 16; ++r) {
        int4 v = base[(size_t)r * (PSTRIDE / 4)];
        acc.x += v.x; acc.y += v.y; acc.z += v.z; acc.w += v.w;
    }
    atomicAdd(&wsi[col4 * 4 + 0], acc.x);
    atomicAdd(&wsi[col4 * 4 + 1], acc.y);
    atomicAdd(&wsi[col4 * 4 + 2], acc.z);
    atomicAdd(&wsi[col4 * 4 + 3], acc.w);
}

// ---------- K2: centers, norms, Gram/diff, sim, final (1 block, 8 waves) ----------
__global__ __launch_bounds__(512) void k2_final(const int* __restrict__ wsi,
                                                float* __restrict__ out) {
    __shared__ __align__(16) float s_cen[C * 260];  // 260 = 65 float4: rows 16B-aligned
    __shared__ __align__(16) float s_u[C * 260];
    __shared__ float s_nc[C];
    __shared__ float s_cntf[C];
    __shared__ float s_pair[C * C];
    __shared__ float s_sim[C];
    const int tid = threadIdx.x;

    if (tid < C) s_cntf[tid] = (float)wsi[OFF_CNT + tid];
    __syncthreads();
    for (int i = tid; i < C * 256; i += 512) {
        int c = i >> 8, d = i & 255;
        float icnt = 1.f / fmaxf(s_cntf[c], 1.f);
        s_cen[c * 260 + d] = (float)wsi[OFF_S + i] * IS_S * icnt;
        s_u[c * 260 + d]   = (float)wsi[OFF_U + i] * IS_U;
    }
    __syncthreads();
    if (tid < C) {
        float nsq = 0.f;
        for (int d = 0; d < D_DIM; ++d) {
            float x = s_cen[tid * 260 + d];
            nsq += x * x;
        }
        s_nc[tid] = sqrtf(nsq);
    }
    __syncthreads();
    if (tid < C * C) {                       // waves 0-5: Gram + diff pairs
        int i = tid / C, j = tid % C;
        const float4* ci = (const float4*)&s_cen[i * 260];
        const float4* cj = (const float4*)&s_cen[j * 260];
        float dot = 0.f;
        #pragma unroll 8
        for (int k = 0; k < 64; ++k) {
            float4 a = ci[k], bb = cj[k];
            dot += a.x * bb.x + a.y * bb.y + a.z * bb.z + a.w * bb.w;
        }
        float S = dot / fmaxf(s_nc[i] * s_nc[j], EPS);
        s_pair[tid] = (i == j) ? (1.f - S) : fmaxf(S, 0.f);
    } else if (tid >= 384 && tid < 384 + C) { // wave 6: sim dots, concurrent with Gram
        int i = tid - 384;
        const float4* ci = (const float4*)&s_cen[i * 260];
        const float4* ui = (const float4*)&s_u[i * 260];
        float dot = 0.f;
        #pragma unroll 8
        for (int k = 0; k < 64; ++k) {
            float4 a = ci[k], bb = ui[k];
            dot += a.x * bb.x + a.y * bb.y + a.z * bb.z + a.w * bb.w;
        }
        // sim_i = 1 - (Σ cos)/cnt = 1 - dot(center,U)/(nc*cnt)
        s_sim[i] = (s_cntf[i] > 0.f)
                 ? (1.f - dot / fmaxf(s_nc[i] * s_cntf[i], EPS)) : 0.f;
    }
    __syncthreads();
    if (tid < C) {
        float row = 0.f;
        for (int j = 0; j < C; ++j) row += s_pair[tid * C + j];
        s_pair[tid * C] = (s_cntf[tid] > 0.f) ? (row * (1.f / (float)C)) : 0.f;
    }
    __syncthreads();
    if (tid == 0) {
        float tot = 0.f;
        for (int i = 0; i < C; ++i) tot += s_pair[i * C] + s_sim[i];
        out[0] = tot;
    }
}

extern "C" void kernel_launch(void* const* d_in, const int* in_sizes, int n_in,
                              void* d_out, int out_size, void* d_ws, size_t ws_size,
                              hipStream_t stream) {
    const float* in  = (const float*)d_in[0];
    const int*   tgt = (const int*)d_in[1];
    float* out = (float*)d_out;
    int*   wsi = (int*)d_ws;

    k1_pass<<<G1, 512, 0, stream>>>(in, tgt, wsi);
    k1b_reduce<<<dim3(10, 32), 256, 0, stream>>>(wsi);
    k2_final<<<1, 512, 0, stream>>>(wsi, out);
}